// Round 8
// baseline (93.239 us; speedup 1.0000x reference)
//
#include <hip/hip_runtime.h>

// B=8, C=21, H=512, W=512 ; gt/pred int32 ; output = scalar f32
// mean over B of tp / max(tp+fp+fn, 1e-8)
//   valid = gt != 255 ; eq = gt==pred ; gt_in = 1<=gt<21 ; pred_in = 1<=pred<21

#define N_CLASSES 21
#define IGNORE_LBL 255
#define BATCH 8
#define THREADS 256
#define WAVES 4
#define BPS 256                   // blocks per sample
#define VEC_PER_SAMPLE 1376256    // int4 per sample
#define VEC_PER_BLOCK 5376        // int4 per block per stream
#define VEC_PER_WAVE 1344         // int4 per wave per stream = 21 tiles
#define GRP 3                     // tiles per group (3 KB runs per stream)
#define NGROUPS 7                 // 21 tiles = 7 groups of 3, no tail
#define TOTAL_BLOCKS (BPS * BATCH)  // 2048
#define DONE_IDX 64               // ws[64] = done counter

typedef __attribute__((address_space(3))) void lds_void;
typedef const __attribute__((address_space(1))) void gbl_void;

__device__ __forceinline__ void proc4(const int4& g, const int4& p,
                                      int& tp, int& fp, int& fn) {
    const int gv[4] = {g.x, g.y, g.z, g.w};
    const int pv[4] = {p.x, p.y, p.z, p.w};
#pragma unroll
    for (int k = 0; k < 4; ++k) {
        const int gk = gv[k], pk = pv[k];
        const int valid = (gk != IGNORE_LBL);
        const int eq = (gk == pk);
        const int gin = (gk >= 1) & (gk < N_CLASSES);
        const int pin = (pk >= 1) & (pk < N_CLASSES);
        tp += eq & gin & valid;
        fp += (eq ^ 1) & pin & valid;
        fn += (eq ^ 1) & gin & valid;
    }
}

// Grouped-stream async ring: per group, issue 3 contiguous 1KB gt tiles then
// 3 contiguous 1KB pred tiles (3KB runs per stream at the memory controller,
// vs 1KB alternation) to improve DRAM page locality of the HBM-miss stream.
// ws layout: u32 counts at ws[b*8 + {0,1,2}], done counter at ws[64].
__global__ __launch_bounds__(THREADS) void iou_fused_kernel(
    const int* __restrict__ gt, const int* __restrict__ pred,
    unsigned int* __restrict__ ws, float* __restrict__ out) {
    // [wave][ringslot 2][stream 2][tile 3][64 int4] = 48 KB
    __shared__ int4 smem[WAVES][2][2][GRP][64];

    const int blk = blockIdx.x;
    const int b = blk >> 8;
    const int seg = blk & 255;
    const int w = threadIdx.x >> 6;
    const int lane = threadIdx.x & 63;

    const size_t base = (size_t)b * VEC_PER_SAMPLE + (size_t)seg * VEC_PER_BLOCK
                        + (size_t)w * VEC_PER_WAVE + lane;
    const int4* __restrict__ g4 = reinterpret_cast<const int4*>(gt) + base;
    const int4* __restrict__ p4 = reinterpret_cast<const int4*>(pred) + base;

#define ISSUE_GROUP(j, slot)                                                     \
    do {                                                                         \
        _Pragma("unroll") for (int k = 0; k < GRP; ++k)                          \
            __builtin_amdgcn_global_load_lds(                                    \
                (gbl_void*)(g4 + ((j) * GRP + k) * 64),                          \
                (lds_void*)&smem[w][slot][0][k][0], 16, 0, 0);                   \
        _Pragma("unroll") for (int k = 0; k < GRP; ++k)                          \
            __builtin_amdgcn_global_load_lds(                                    \
                (gbl_void*)(p4 + ((j) * GRP + k) * 64),                          \
                (lds_void*)&smem[w][slot][1][k][0], 16, 0, 0);                   \
    } while (0)

    // prologue: two groups in flight (12 loads, 12 KB/wave)
    ISSUE_GROUP(0, 0);
    ISSUE_GROUP(1, 1);

    int tp = 0, fp = 0, fn = 0;

#pragma unroll
    for (int j = 0; j < NGROUPS; ++j) {
        const int slot = j & 1;
        if (j < NGROUPS - 1) {
            asm volatile("s_waitcnt vmcnt(6)" ::: "memory");  // group j done
        } else {
            asm volatile("s_waitcnt vmcnt(0)" ::: "memory");  // last group
        }
#pragma unroll
        for (int k = 0; k < GRP; ++k) {
            int4 g = smem[w][slot][0][k][lane];
            int4 p = smem[w][slot][1][k][lane];
            proc4(g, p, tp, fp, fn);
        }
        // drain ds_reads before overwriting this slot; pin program order
        asm volatile("s_waitcnt lgkmcnt(0)" ::: "memory");
        __builtin_amdgcn_sched_barrier(0);
        if (j + 2 < NGROUPS) ISSUE_GROUP(j + 2, slot);
    }
#undef ISSUE_GROUP

    // wave (64-lane) reduce
#pragma unroll
    for (int off = 32; off > 0; off >>= 1) {
        tp += __shfl_down(tp, off);
        fp += __shfl_down(fp, off);
        fn += __shfl_down(fn, off);
    }

    __shared__ int s_tp[WAVES], s_fp[WAVES], s_fn[WAVES];
    if (lane == 0) {
        s_tp[w] = tp;
        s_fp[w] = fp;
        s_fn[w] = fn;
    }
    __syncthreads();

    if (threadIdx.x == 0) {
        int t = 0, f = 0, n = 0;
#pragma unroll
        for (int wv = 0; wv < WAVES; ++wv) {
            t += s_tp[wv];
            f += s_fp[wv];
            n += s_fn[wv];
        }
        atomicAdd(&ws[b * 8 + 0], (unsigned int)t);
        atomicAdd(&ws[b * 8 + 1], (unsigned int)f);
        atomicAdd(&ws[b * 8 + 2], (unsigned int)n);

        // NO __threadfence (L2-flush poison, r2-r4). Atomics serialize at the
        // device coherence point; vmcnt(0) guarantees this block's count-adds
        // are in the serialized history before the done-increment is visible.
        asm volatile("s_waitcnt vmcnt(0)" ::: "memory");
        const unsigned int prev = atomicAdd(&ws[DONE_IDX], 1u);
        if (prev == TOTAL_BLOCKS - 1) {
            float s = 0.0f;
#pragma unroll
            for (int bb = 0; bb < BATCH; ++bb) {
                const float tpf = (float)atomicAdd(&ws[bb * 8 + 0], 0u);
                const float fpf = (float)atomicAdd(&ws[bb * 8 + 1], 0u);
                const float fnf = (float)atomicAdd(&ws[bb * 8 + 2], 0u);
                s += tpf / fmaxf(tpf + fpf + fnf, 1e-8f);
            }
            out[0] = s / (float)BATCH;
        }
    }
}

extern "C" void kernel_launch(void* const* d_in, const int* in_sizes, int n_in,
                              void* d_out, int out_size, void* d_ws, size_t ws_size,
                              hipStream_t stream) {
    const int* gt = (const int*)d_in[0];
    const int* pred = (const int*)d_in[1];
    float* out = (float*)d_out;
    unsigned int* ws = (unsigned int*)d_ws;

    hipMemsetAsync(ws, 0, (DONE_IDX + 1) * sizeof(unsigned int), stream);

    dim3 grid(TOTAL_BLOCKS, 1, 1);
    dim3 block(THREADS, 1, 1);
    iou_fused_kernel<<<grid, block, 0, stream>>>(gt, pred, ws, out);
}

// Round 9
// 64.788 us; speedup vs baseline: 1.4391x; 1.4391x over previous
//
#include <hip/hip_runtime.h>

// B=8, C=21, H=512, W=512 ; gt/pred int32 ; output = scalar f32
// mean over B of tp / max(tp+fp+fn, 1e-8)
//   valid = gt != 255 ; eq = gt==pred ; gt_in = 1<=gt<21 ; pred_in = 1<=pred<21

#define N_CLASSES 21
#define IGNORE_LBL 255
#define BATCH 8
#define BPS 256                  // blocks per sample
#define THREADS 256
#define VEC_PER_SAMPLE 1376256   // int4 per sample (21*512*512/4)
#define STRIDE (BPS * THREADS)   // 65536 int4 = 1 MB
#define UNROLL 3                 // 21 = 7 outer x 3 inner, no tail
#define TOTAL_BLOCKS (BPS * BATCH)  // 2048

__device__ __forceinline__ void proc4(const int4& g, const int4& p,
                                      int& tp, int& fp, int& fn) {
    const int gv[4] = {g.x, g.y, g.z, g.w};
    const int pv[4] = {p.x, p.y, p.z, p.w};
#pragma unroll
    for (int k = 0; k < 4; ++k) {
        const int gk = gv[k], pk = pv[k];
        const int valid = (gk != IGNORE_LBL);
        const int eq = (gk == pk);
        const int gin = (gk >= 1) & (gk < N_CLASSES);
        const int pin = (pk >= 1) & (pk < N_CLASSES);
        tp += eq & gin & valid;
        fp += (eq ^ 1) & pin & valid;
        fn += (eq ^ 1) & gin & valid;
    }
}

// Per-block partials WRITTEN (not atomic) to ws[blk] — no atomics, no memset,
// no fence. ws = int4[2048] (32 KB), fully overwritten every call.
__global__ __launch_bounds__(THREADS) void iou_count_kernel(
    const int* __restrict__ gt, const int* __restrict__ pred,
    int4* __restrict__ parts) {
    const int b = blockIdx.y;
    const int4* __restrict__ g4 =
        reinterpret_cast<const int4*>(gt) + (size_t)b * VEC_PER_SAMPLE;
    const int4* __restrict__ p4 =
        reinterpret_cast<const int4*>(pred) + (size_t)b * VEC_PER_SAMPLE;

    int i = blockIdx.x * THREADS + threadIdx.x;
    int tp = 0, fp = 0, fn = 0;

    // 6 independent dwordx4 loads per outer iter; sched_barrier keeps the
    // load group ahead of the consume group (r5-proven structure, widened).
#pragma unroll 1
    for (int o = 0; o < 7; ++o) {
        int4 g[UNROLL], p[UNROLL];
#pragma unroll
        for (int k = 0; k < UNROLL; ++k) {
            g[k] = g4[i + k * STRIDE];
            p[k] = p4[i + k * STRIDE];
        }
        __builtin_amdgcn_sched_barrier(0);
#pragma unroll
        for (int k = 0; k < UNROLL; ++k) proc4(g[k], p[k], tp, fp, fn);
        i += UNROLL * STRIDE;
    }

    // wave (64-lane) reduce
#pragma unroll
    for (int off = 32; off > 0; off >>= 1) {
        tp += __shfl_down(tp, off);
        fp += __shfl_down(fp, off);
        fn += __shfl_down(fn, off);
    }

    __shared__ int s_tp[4], s_fp[4], s_fn[4];  // 256 threads = 4 waves
    const int wave = threadIdx.x >> 6;
    const int lane = threadIdx.x & 63;
    if (lane == 0) {
        s_tp[wave] = tp;
        s_fp[wave] = fp;
        s_fn[wave] = fn;
    }
    __syncthreads();
    if (threadIdx.x == 0) {
        int t = 0, f = 0, n = 0;
#pragma unroll
        for (int w = 0; w < 4; ++w) {
            t += s_tp[w];
            f += s_fp[w];
            n += s_fn[w];
        }
        parts[b * BPS + blockIdx.x] = make_int4(t, f, n, 0);
    }
}

// 8 waves, wave w reduces sample w's 256 partials (64 lanes x 4 int4, coalesced)
__global__ __launch_bounds__(512) void iou_final_kernel(
    const int4* __restrict__ parts, float* __restrict__ out) {
    const int w = threadIdx.x >> 6;   // sample
    const int lane = threadIdx.x & 63;

    int t = 0, f = 0, n = 0;
#pragma unroll
    for (int k = 0; k < 4; ++k) {
        const int4 v = parts[w * BPS + k * 64 + lane];
        t += v.x;
        f += v.y;
        n += v.z;
    }
#pragma unroll
    for (int off = 32; off > 0; off >>= 1) {
        t += __shfl_down(t, off);
        f += __shfl_down(f, off);
        n += __shfl_down(n, off);
    }

    __shared__ float jac[BATCH];
    if (lane == 0) {
        const float tp = (float)t, fp = (float)f, fn = (float)n;
        jac[w] = tp / fmaxf(tp + fp + fn, 1e-8f);
    }
    __syncthreads();
    if (threadIdx.x == 0) {
        float s = 0.0f;
#pragma unroll
        for (int b = 0; b < BATCH; ++b) s += jac[b];
        out[0] = s / (float)BATCH;
    }
}

extern "C" void kernel_launch(void* const* d_in, const int* in_sizes, int n_in,
                              void* d_out, int out_size, void* d_ws, size_t ws_size,
                              hipStream_t stream) {
    const int* gt = (const int*)d_in[0];
    const int* pred = (const int*)d_in[1];
    float* out = (float*)d_out;
    int4* parts = (int4*)d_ws;  // 2048 * 16 B = 32 KB

    dim3 grid(BPS, BATCH, 1);
    dim3 block(THREADS, 1, 1);
    iou_count_kernel<<<grid, block, 0, stream>>>(gt, pred, parts);
    iou_final_kernel<<<1, 512, 0, stream>>>(parts, out);
}